// Round 6
// baseline (219.767 us; speedup 1.0000x reference)
//
#include <hip/hip_runtime.h>

#define SEQ 4096
#define KDIM 1024
#define NQKV 3072
#define BK 32

typedef __bf16 bf16x8 __attribute__((ext_vector_type(8)));
typedef float  f32x4  __attribute__((ext_vector_type(4)));

#define WAITV(n) asm volatile("s_waitcnt vmcnt(" #n ")" ::: "memory")
#define BAR()    asm volatile("s_barrier" ::: "memory")

__device__ __forceinline__ unsigned short f2b(float f) {
    unsigned int u = __float_as_uint(f);
    u += 0x7FFFu + ((u >> 16) & 1u);   // round-to-nearest-even
    return (unsigned short)(u >> 16);
}
__device__ __forceinline__ float b2f(unsigned short h) {
    return __uint_as_float(((unsigned int)h) << 16);
}

__device__ __forceinline__ void gld_lds16(const unsigned short* g, unsigned short* l) {
    __builtin_amdgcn_global_load_lds(
        (const __attribute__((address_space(1))) void*)g,
        (__attribute__((address_space(3))) void*)l, 16, 0, 0);
}

// ---------------------------------------------------------------------------
// 3-stage software-pipelined 128x128x32 MFMA tile loop, XOR-swizzled LDS.
// 48 KB LDS -> 3 blocks/CU (64 KB/4-stage killed occupancy: R5 regression).
// Per iter: WAITV(4) [own stage-k loads done; stage k+1 stays in flight
// across the barrier]; s_barrier; issue stage k+2 into buf (k-1)%3 (whose
// reads retired before this barrier in all waves); compute k.
// ---------------------------------------------------------------------------
__device__ __forceinline__ void stage_tiles(
    const unsigned short* Ag, int lda, const unsigned short* Bg, int ldb,
    int k0, unsigned short* sA, unsigned short* sB, int wave, int lane)
{
    #pragma unroll
    for (int i = 0; i < 2; ++i) {
        int c = wave * 128 + i * 64 + lane;        // chunk id 0..511
        int row = c >> 2, slot = c & 3;
        int p = slot ^ ((row >> 1) & 3);           // XOR-swizzled piece
        gld_lds16(Ag + row * lda + k0 + p * 8, sA + (wave * 2 + i) * 512);
        gld_lds16(Bg + row * ldb + k0 + p * 8, sB + (wave * 2 + i) * 512);
    }
}

__device__ __forceinline__ const unsigned short* frag_addr(
    const unsigned short* s, int row, int quad)
{
    return s + row * 32 + (quad ^ ((row >> 1) & 3)) * 8;
}

__device__ __forceinline__ void compute_tile(
    const unsigned short* sA, const unsigned short* sB, f32x4 acc[4][4],
    int wm, int wn, int lr, int quad)
{
    bf16x8 af[4], bq[4];
    #pragma unroll
    for (int i = 0; i < 4; ++i)
        af[i] = *(const bf16x8*)frag_addr(sA, wm + 16 * i + lr, quad);
    #pragma unroll
    for (int j = 0; j < 4; ++j)
        bq[j] = *(const bf16x8*)frag_addr(sB, wn + 16 * j + lr, quad);
    #pragma unroll
    for (int i = 0; i < 4; ++i)
        #pragma unroll
        for (int j = 0; j < 4; ++j)
            acc[i][j] = __builtin_amdgcn_mfma_f32_16x16x32_bf16(af[i], bq[j], acc[i][j], 0, 0, 0);
}

__device__ __forceinline__ void mfma_pipe(
    const unsigned short* Ag, int lda, const unsigned short* Bg, int ldb,
    int kLen, unsigned short* lds, f32x4 acc[4][4])
{
    const int tid  = threadIdx.x;
    const int wave = tid >> 6, lane = tid & 63;
    const int lr   = lane & 15, quad = lane >> 4;
    const int wm   = (wave >> 1) * 64, wn = (wave & 1) * 64;
    const int niter = kLen >> 5;

    #pragma unroll
    for (int s = 0; s < 2; ++s)
        if (s < niter)
            stage_tiles(Ag, lda, Bg, ldb, s * BK,
                        lds + s * 8192, lds + s * 8192 + 4096, wave, lane);

    #pragma unroll 1
    for (int k = 0; k < niter; ++k) {
        if (k + 1 < niter) WAITV(4);    // stage k done; k+1 stays in flight
        else               WAITV(0);
        BAR();
        if (k + 2 < niter) {
            const int s = (k + 2) % 3;
            stage_tiles(Ag, lda, Bg, ldb, (k + 2) * BK,
                        lds + s * 8192, lds + s * 8192 + 4096, wave, lane);
        }
        const int c = k % 3;
        compute_tile(lds + c * 8192, lds + c * 8192 + 4096, acc, wm, wn, lr, quad);
    }
}

__device__ __forceinline__ void zero_acc(f32x4 acc[4][4]) {
    const f32x4 z = {0.f, 0.f, 0.f, 0.f};
    #pragma unroll
    for (int i = 0; i < 4; ++i)
        #pragma unroll
        for (int j = 0; j < 4; ++j) acc[i][j] = z;
}

// ---------------------------------------------------------------------------
// Epilogue: wave-private LDS restage -> 16B coalesced bf16 stores.
// ---------------------------------------------------------------------------
__device__ __forceinline__ void store_rows_bf16(
    f32x4 acc[4][4], unsigned short* Cw, int ld, unsigned short* lw, int lane)
{
    const int lr = lane & 15, quad = lane >> 4;
    #pragma unroll
    for (int i = 0; i < 4; ++i) {
        #pragma unroll
        for (int j = 0; j < 4; ++j)
            #pragma unroll
            for (int r = 0; r < 4; ++r)
                lw[(quad * 4 + r) * 72 + j * 16 + lr] = f2b(acc[i][j][r]);
        #pragma unroll
        for (int t = 0; t < 2; ++t) {
            int chunk = t * 64 + lane;          // 0..127
            int rl = chunk >> 3, c8 = chunk & 7;
            uint4 v = *(const uint4*)(lw + rl * 72 + c8 * 8);
            *(uint4*)(Cw + (16 * i + rl) * ld + c8 * 8) = v;
        }
    }
}

// Transposed (Vt[d][s]): each lane stores 8 consecutive s for one d.
__device__ __forceinline__ void store_cols_bf16(
    f32x4 acc[4][4], unsigned short* Vw, unsigned short* lw, int lane)
{
    const int lr = lane & 15, quad = lane >> 4;
    #pragma unroll
    for (int ip = 0; ip < 2; ++ip) {            // 32 s-rows per pass
        #pragma unroll
        for (int ii = 0; ii < 2; ++ii)
            #pragma unroll
            for (int j = 0; j < 4; ++j)
                #pragma unroll
                for (int r = 0; r < 4; ++r)
                    lw[(j * 16 + lr) * 40 + ii * 16 + quad * 4 + r] = f2b(acc[ip * 2 + ii][j][r]);
        #pragma unroll
        for (int t = 0; t < 4; ++t) {
            int chunk = t * 64 + lane;          // 0..255
            int col = chunk >> 2, c8 = chunk & 3;
            uint4 v = *(const uint4*)(lw + col * 40 + c8 * 8);
            *(uint4*)(Vw + col * SEQ + ip * 32 + c8 * 8) = v;
        }
    }
}

// ---------------------------------------------------------------------------
// Kernel 0: fused prep. [0,4096): x->bf16; [4096,8192): zero d_out;
// [8192,11264): W transpose; block 11264: zero lrow[4096].
// ---------------------------------------------------------------------------
__global__ __launch_bounds__(256) void prep(
    const float* __restrict__ x, unsigned short* __restrict__ Xb,
    const float* __restrict__ W, unsigned short* __restrict__ Wt,
    float4* __restrict__ out, float4* __restrict__ lrow)
{
    __shared__ float tile[32][33];
    const int b = blockIdx.x, tid = threadIdx.x;
    if (b < 4096) {
        int i = (b * 256 + tid) * 4;
        float4 v = *(const float4*)(x + i);
        ushort4 o;
        o.x = f2b(v.x); o.y = f2b(v.y); o.z = f2b(v.z); o.w = f2b(v.w);
        *(ushort4*)(Xb + i) = o;
    } else if (b < 8192) {
        const float4 z = {0.f, 0.f, 0.f, 0.f};
        out[(b - 4096) * 256 + tid] = z;
    } else if (b < 11264) {
        const int bb = b - 8192;
        const int n0 = (bb % 96) * 32, k0 = (bb / 96) * 32;
        const int c = tid & 31, r0 = tid >> 5;
        #pragma unroll
        for (int r = r0; r < 32; r += 8)
            tile[r][c] = W[(k0 + r) * NQKV + n0 + c];
        __syncthreads();
        #pragma unroll
        for (int r = r0; r < 32; r += 8)
            Wt[(n0 + r) * KDIM + k0 + c] = f2b(tile[c][r]);
    } else {
        const float4 z = {0.f, 0.f, 0.f, 0.f};
        #pragma unroll
        for (int k = 0; k < 4; ++k) lrow[tid * 4 + k] = z;
    }
}

// ---------------------------------------------------------------------------
// Kernel 1: qvk = Xb @ Wt^T -> Q rows, K rows, V transposed (Vt[d][s])
// Grid (m=32, n=24): lin%8 = m%8 -> same Xb tile co-resident per XCD L2.
// ---------------------------------------------------------------------------
__global__ __launch_bounds__(256) void qvk_gemm(
    const unsigned short* __restrict__ Xb, const unsigned short* __restrict__ Wt,
    unsigned short* __restrict__ Qb, unsigned short* __restrict__ Kb,
    unsigned short* __restrict__ Vt)
{
    __shared__ __align__(16) unsigned short lds[24576];   // 48 KiB
    const int m0 = blockIdx.x * 128;
    const int n0 = blockIdx.y * 128;
    f32x4 acc[4][4];
    zero_acc(acc);
    mfma_pipe(Xb + m0 * KDIM, KDIM, Wt + n0 * KDIM, KDIM, KDIM, lds, acc);
    __syncthreads();

    const int lane = threadIdx.x & 63, wave = threadIdx.x >> 6;
    const int wm = (wave >> 1) * 64, wn = (wave & 1) * 64;
    unsigned short* lw = lds + wave * 2560;
    const int region = n0 >> 10;
    const int nloc = n0 & 1023;
    if (region == 0)
        store_rows_bf16(acc, Qb + (m0 + wm) * KDIM + nloc + wn, KDIM, lw, lane);
    else if (region == 2)
        store_rows_bf16(acc, Kb + (m0 + wm) * KDIM + nloc + wn, KDIM, lw, lane);
    else
        store_cols_bf16(acc, Vt + (nloc + wn) * SEQ + m0 + wm, lw, lane);
}

// ---------------------------------------------------------------------------
// Kernel 2: fused score+exp. P = exp((Q@K^T)/32) causal (no max-sub: |s|<=16
// by Cauchy-Schwarz). Row sums atomicAdd into lrow; P bf16 to Sb.
// Grid (bm=32, bn=32), early-exit bn>bm.
// ---------------------------------------------------------------------------
__global__ __launch_bounds__(256) void score_exp_gemm(
    const unsigned short* __restrict__ Qb, const unsigned short* __restrict__ Kb,
    unsigned short* __restrict__ Sb, float* __restrict__ lrow)
{
    __shared__ __align__(16) unsigned short lds[24576];
    const int bm = blockIdx.x, bn = blockIdx.y;
    if (bn > bm) return;
    const int m0 = bm * 128, n0 = bn * 128;

    f32x4 acc[4][4];
    zero_acc(acc);
    mfma_pipe(Qb + m0 * KDIM, KDIM, Kb + n0 * KDIM, KDIM, KDIM, lds, acc);

    const int lane = threadIdx.x & 63, wave = threadIdx.x >> 6;
    const int lr = lane & 15, quad = lane >> 4;
    const int wm = (wave >> 1) * 64, wn = (wave & 1) * 64;
    #pragma unroll
    for (int i = 0; i < 4; ++i)
        #pragma unroll
        for (int j = 0; j < 4; ++j)
            #pragma unroll
            for (int r = 0; r < 4; ++r) {
                float v = __expf(acc[i][j][r] * 0.03125f);
                if (bm == bn) {
                    int row = wm + 16 * i + quad * 4 + r;
                    int col = wn + 16 * j + lr;
                    if (col > row) v = 0.f;
                }
                acc[i][j][r] = v;
            }
    #pragma unroll
    for (int i = 0; i < 4; ++i)
        #pragma unroll
        for (int r = 0; r < 4; ++r) {
            float s = acc[i][0][r] + acc[i][1][r] + acc[i][2][r] + acc[i][3][r];
            s += __shfl_xor(s, 1, 16);
            s += __shfl_xor(s, 2, 16);
            s += __shfl_xor(s, 4, 16);
            s += __shfl_xor(s, 8, 16);
            if (lr == 0)
                atomicAdd(&lrow[m0 + wm + 16 * i + quad * 4 + r], s);
        }
    __syncthreads();
    store_rows_bf16(acc, Sb + (m0 + wm) * SEQ + n0 + wn, SEQ, lds + wave * 2560, lane);
}

// ---------------------------------------------------------------------------
// Kernel 3: out = (P @ V) / l, split-K in 512-wide chunks over the causal
// extent. 144 (m,c) pairs x 8 n = 1152 blocks (4.5/CU): kLen spread 128..512.
// Grid (pair, n): pair stride 144 % 8 == 0 -> the 8 n-blocks sharing one Sb
// chunk land on one XCD.
// ---------------------------------------------------------------------------
__global__ __launch_bounds__(256) void pv_gemm(
    const unsigned short* __restrict__ Sb, const unsigned short* __restrict__ Vt,
    const float* __restrict__ lrow, float* __restrict__ out)
{
    __shared__ __align__(16) unsigned short lds[24576];
    const int n0 = blockIdx.y * 128;
    const int y = blockIdx.x;               // 0..143
    // group g: m in [4g, 4g+4) has g+1 chunks of 512
    int g = 0, base = 0;
    while (y >= base + 4 * (g + 1)) { base += 4 * (g + 1); ++g; }
    const int yy = y - base;
    const int m = 4 * g + yy / (g + 1);
    const int c = yy % (g + 1);
    const int m0 = m * 128;
    const int kstart = c * 512;
    const int kend = min((m + 1) * 128, kstart + 512);

    f32x4 acc[4][4];
    zero_acc(acc);
    mfma_pipe(Sb + m0 * SEQ + kstart, SEQ, Vt + n0 * SEQ + kstart, SEQ,
              kend - kstart, lds, acc);

    const int lane = threadIdx.x & 63, wave = threadIdx.x >> 6;
    const int lr = lane & 15, quad = lane >> 4;
    const int wm = (wave >> 1) * 64, wn = (wave & 1) * 64;
    #pragma unroll
    for (int i = 0; i < 4; ++i) {
        const int rbase = m0 + wm + 16 * i + quad * 4;
        const float4 l4 = *(const float4*)(lrow + rbase);
        float inv[4] = {1.0f / l4.x, 1.0f / l4.y, 1.0f / l4.z, 1.0f / l4.w};
        #pragma unroll
        for (int j = 0; j < 4; ++j) {
            const int col = n0 + wn + 16 * j + lr;
            if (g == 0) {                     // single-chunk m-tiles: store
                #pragma unroll
                for (int r = 0; r < 4; ++r)
                    out[(rbase + r) * KDIM + col] = acc[i][j][r] * inv[r];
            } else {
                #pragma unroll
                for (int r = 0; r < 4; ++r)
                    atomicAdd(&out[(rbase + r) * KDIM + col], acc[i][j][r] * inv[r]);
            }
        }
    }
}

// ---------------------------------------------------------------------------
extern "C" void kernel_launch(void* const* d_in, const int* in_sizes, int n_in,
                              void* d_out, int out_size, void* d_ws, size_t ws_size,
                              hipStream_t stream) {
    const float* x = (const float*)d_in[0];   // [4096][1024]
    const float* W = (const float*)d_in[1];   // [1024][3072]
    float* out = (float*)d_out;               // [4096][1024]
    char* ws = (char*)d_ws;

    unsigned short* Xb = (unsigned short*)(ws);                     //  8 MiB
    unsigned short* Wt = (unsigned short*)(ws + 8388608);           //  6 MiB
    unsigned short* Qb = (unsigned short*)(ws + 14680064);          //  8 MiB
    unsigned short* Kb = (unsigned short*)(ws + 23068672);          //  8 MiB
    unsigned short* Vt = (unsigned short*)(ws + 31457280);          //  8 MiB
    unsigned short* Sb = (unsigned short*)(ws + 39845888);          // 32 MiB
    float*        lrow = (float*)(ws + 73400320);                   // 16 KiB

    prep          <<<11265, 256, 0, stream>>>(x, Xb, W, Wt, (float4*)out, (float4*)lrow);
    qvk_gemm      <<<dim3(SEQ / 128, NQKV / 128), 256, 0, stream>>>(Xb, Wt, Qb, Kb, Vt);
    score_exp_gemm<<<dim3(SEQ / 128, SEQ / 128), 256, 0, stream>>>(Qb, Kb, Sb, lrow);
    pv_gemm       <<<dim3(144, KDIM / 128), 256, 0, stream>>>(Sb, Vt, lrow, out);
}

// Round 7
// 199.060 us; speedup vs baseline: 1.1040x; 1.1040x over previous
//
#include <hip/hip_runtime.h>

#define SEQ 4096
#define KDIM 1024
#define NQKV 3072
#define BK 32

typedef __bf16 bf16x8 __attribute__((ext_vector_type(8)));
typedef float  f32x4  __attribute__((ext_vector_type(4)));

#define WAITV(n) asm volatile("s_waitcnt vmcnt(" #n ")" ::: "memory")
#define BAR()    asm volatile("s_barrier" ::: "memory")

__device__ __forceinline__ unsigned short f2b(float f) {
    unsigned int u = __float_as_uint(f);
    u += 0x7FFFu + ((u >> 16) & 1u);   // round-to-nearest-even
    return (unsigned short)(u >> 16);
}
__device__ __forceinline__ float b2f(unsigned short h) {
    return __uint_as_float(((unsigned int)h) << 16);
}

__device__ __forceinline__ void gld_lds16(const unsigned short* g, unsigned short* l) {
    __builtin_amdgcn_global_load_lds(
        (const __attribute__((address_space(1))) void*)g,
        (__attribute__((address_space(3))) void*)l, 16, 0, 0);
}

// ---------------------------------------------------------------------------
// Shared pieces: XOR-swizzled staging + fragment reads + MFMA compute.
// ---------------------------------------------------------------------------
__device__ __forceinline__ void stage_tiles(
    const unsigned short* Ag, int lda, const unsigned short* Bg, int ldb,
    int k0, unsigned short* sA, unsigned short* sB, int wave, int lane)
{
    #pragma unroll
    for (int i = 0; i < 2; ++i) {
        int c = wave * 128 + i * 64 + lane;        // chunk id 0..511
        int row = c >> 2, slot = c & 3;
        int p = slot ^ ((row >> 1) & 3);           // XOR-swizzled piece
        gld_lds16(Ag + row * lda + k0 + p * 8, sA + (wave * 2 + i) * 512);
        gld_lds16(Bg + row * ldb + k0 + p * 8, sB + (wave * 2 + i) * 512);
    }
}

__device__ __forceinline__ const unsigned short* frag_addr(
    const unsigned short* s, int row, int quad)
{
    return s + row * 32 + (quad ^ ((row >> 1) & 3)) * 8;
}

__device__ __forceinline__ void compute_tile(
    const unsigned short* sA, const unsigned short* sB, f32x4 acc[4][4],
    int wm, int wn, int lr, int quad)
{
    bf16x8 af[4], bq[4];
    #pragma unroll
    for (int i = 0; i < 4; ++i)
        af[i] = *(const bf16x8*)frag_addr(sA, wm + 16 * i + lr, quad);
    #pragma unroll
    for (int j = 0; j < 4; ++j)
        bq[j] = *(const bf16x8*)frag_addr(sB, wn + 16 * j + lr, quad);
    #pragma unroll
    for (int i = 0; i < 4; ++i)
        #pragma unroll
        for (int j = 0; j < 4; ++j)
            acc[i][j] = __builtin_amdgcn_mfma_f32_16x16x32_bf16(af[i], bq[j], acc[i][j], 0, 0, 0);
}

// 3-stage vmcnt-gated pipe (48 KB LDS) — for the K=1024 GEMMs (qvk, score).
__device__ __forceinline__ void mfma_pipe(
    const unsigned short* Ag, int lda, const unsigned short* Bg, int ldb,
    int kLen, unsigned short* lds, f32x4 acc[4][4])
{
    const int tid  = threadIdx.x;
    const int wave = tid >> 6, lane = tid & 63;
    const int lr   = lane & 15, quad = lane >> 4;
    const int wm   = (wave >> 1) * 64, wn = (wave & 1) * 64;
    const int niter = kLen >> 5;

    #pragma unroll
    for (int s = 0; s < 2; ++s)
        if (s < niter)
            stage_tiles(Ag, lda, Bg, ldb, s * BK,
                        lds + s * 8192, lds + s * 8192 + 4096, wave, lane);

    #pragma unroll 1
    for (int k = 0; k < niter; ++k) {
        if (k + 1 < niter) WAITV(4);    // stage k done; k+1 stays in flight
        else               WAITV(0);
        BAR();
        if (k + 2 < niter) {
            const int s = (k + 2) % 3;
            stage_tiles(Ag, lda, Bg, ldb, (k + 2) * BK,
                        lds + s * 8192, lds + s * 8192 + 4096, wave, lane);
        }
        const int c = k % 3;
        compute_tile(lds + c * 8192, lds + c * 8192 + 4096, acc, wm, wn, lr, quad);
    }
}

// 2-stage __syncthreads double-buffer (32 KB LDS) — R4-proven, for pv.
__device__ __forceinline__ void mfma_db(
    const unsigned short* Ag, int lda, const unsigned short* Bg, int ldb,
    int kLen, unsigned short* lds, f32x4 acc[4][4])
{
    const int tid  = threadIdx.x;
    const int wave = tid >> 6, lane = tid & 63;
    const int lr   = lane & 15, quad = lane >> 4;
    const int wm   = (wave >> 1) * 64, wn = (wave & 1) * 64;
    unsigned short* sA0 = lds;
    unsigned short* sB0 = lds + 4096;
    unsigned short* sA1 = lds + 8192;
    unsigned short* sB1 = lds + 12288;

    stage_tiles(Ag, lda, Bg, ldb, 0, sA0, sB0, wave, lane);
    int k = BK;
    #pragma unroll 1
    for (; k + BK < kLen; k += 2 * BK) {
        __syncthreads();
        stage_tiles(Ag, lda, Bg, ldb, k, sA1, sB1, wave, lane);
        compute_tile(sA0, sB0, acc, wm, wn, lr, quad);
        __syncthreads();
        stage_tiles(Ag, lda, Bg, ldb, k + BK, sA0, sB0, wave, lane);
        compute_tile(sA1, sB1, acc, wm, wn, lr, quad);
    }
    if (k < kLen) {
        __syncthreads();
        stage_tiles(Ag, lda, Bg, ldb, k, sA1, sB1, wave, lane);
        compute_tile(sA0, sB0, acc, wm, wn, lr, quad);
        __syncthreads();
        compute_tile(sA1, sB1, acc, wm, wn, lr, quad);
    } else {
        __syncthreads();
        compute_tile(sA0, sB0, acc, wm, wn, lr, quad);
    }
}

__device__ __forceinline__ void zero_acc(f32x4 acc[4][4]) {
    const f32x4 z = {0.f, 0.f, 0.f, 0.f};
    #pragma unroll
    for (int i = 0; i < 4; ++i)
        #pragma unroll
        for (int j = 0; j < 4; ++j) acc[i][j] = z;
}

// ---------------------------------------------------------------------------
// Epilogue: wave-private LDS restage -> 16B coalesced bf16 stores.
// ---------------------------------------------------------------------------
__device__ __forceinline__ void store_rows_bf16(
    f32x4 acc[4][4], unsigned short* Cw, int ld, unsigned short* lw, int lane)
{
    const int lr = lane & 15, quad = lane >> 4;
    #pragma unroll
    for (int i = 0; i < 4; ++i) {
        #pragma unroll
        for (int j = 0; j < 4; ++j)
            #pragma unroll
            for (int r = 0; r < 4; ++r)
                lw[(quad * 4 + r) * 72 + j * 16 + lr] = f2b(acc[i][j][r]);
        #pragma unroll
        for (int t = 0; t < 2; ++t) {
            int chunk = t * 64 + lane;          // 0..127
            int rl = chunk >> 3, c8 = chunk & 7;
            uint4 v = *(const uint4*)(lw + rl * 72 + c8 * 8);
            *(uint4*)(Cw + (16 * i + rl) * ld + c8 * 8) = v;
        }
    }
}

// Transposed (Vt[d][s]): each lane stores 8 consecutive s for one d.
__device__ __forceinline__ void store_cols_bf16(
    f32x4 acc[4][4], unsigned short* Vw, unsigned short* lw, int lane)
{
    const int lr = lane & 15, quad = lane >> 4;
    #pragma unroll
    for (int ip = 0; ip < 2; ++ip) {            // 32 s-rows per pass
        #pragma unroll
        for (int ii = 0; ii < 2; ++ii)
            #pragma unroll
            for (int j = 0; j < 4; ++j)
                #pragma unroll
                for (int r = 0; r < 4; ++r)
                    lw[(j * 16 + lr) * 40 + ii * 16 + quad * 4 + r] = f2b(acc[ip * 2 + ii][j][r]);
        #pragma unroll
        for (int t = 0; t < 4; ++t) {
            int chunk = t * 64 + lane;          // 0..255
            int col = chunk >> 2, c8 = chunk & 3;
            uint4 v = *(const uint4*)(lw + col * 40 + c8 * 8);
            *(uint4*)(Vw + col * SEQ + ip * 32 + c8 * 8) = v;
        }
    }
}

// ---------------------------------------------------------------------------
// Kernel 0: fused prep. [0,4096): x->bf16; [4096,8192): zero d_out;
// [8192,11264): W transpose; block 11264: zero lrow[4096].
// ---------------------------------------------------------------------------
__global__ __launch_bounds__(256) void prep(
    const float* __restrict__ x, unsigned short* __restrict__ Xb,
    const float* __restrict__ W, unsigned short* __restrict__ Wt,
    float4* __restrict__ out, float4* __restrict__ lrow)
{
    __shared__ float tile[32][33];
    const int b = blockIdx.x, tid = threadIdx.x;
    if (b < 4096) {
        int i = (b * 256 + tid) * 4;
        float4 v = *(const float4*)(x + i);
        ushort4 o;
        o.x = f2b(v.x); o.y = f2b(v.y); o.z = f2b(v.z); o.w = f2b(v.w);
        *(ushort4*)(Xb + i) = o;
    } else if (b < 8192) {
        const float4 z = {0.f, 0.f, 0.f, 0.f};
        out[(b - 4096) * 256 + tid] = z;
    } else if (b < 11264) {
        const int bb = b - 8192;
        const int n0 = (bb % 96) * 32, k0 = (bb / 96) * 32;
        const int c = tid & 31, r0 = tid >> 5;
        #pragma unroll
        for (int r = r0; r < 32; r += 8)
            tile[r][c] = W[(k0 + r) * NQKV + n0 + c];
        __syncthreads();
        #pragma unroll
        for (int r = r0; r < 32; r += 8)
            Wt[(n0 + r) * KDIM + k0 + c] = f2b(tile[c][r]);
    } else {
        const float4 z = {0.f, 0.f, 0.f, 0.f};
        #pragma unroll
        for (int k = 0; k < 4; ++k) lrow[tid * 4 + k] = z;
    }
}

// ---------------------------------------------------------------------------
// Kernel 1: qvk = Xb @ Wt^T -> Q rows, K rows, V transposed (Vt[d][s])
// Grid (m=32, n=24): lin%8 = m%8 -> same Xb tile co-resident per XCD L2.
// ---------------------------------------------------------------------------
__global__ __launch_bounds__(256) void qvk_gemm(
    const unsigned short* __restrict__ Xb, const unsigned short* __restrict__ Wt,
    unsigned short* __restrict__ Qb, unsigned short* __restrict__ Kb,
    unsigned short* __restrict__ Vt)
{
    __shared__ __align__(16) unsigned short lds[24576];   // 48 KiB
    const int m0 = blockIdx.x * 128;
    const int n0 = blockIdx.y * 128;
    f32x4 acc[4][4];
    zero_acc(acc);
    mfma_pipe(Xb + m0 * KDIM, KDIM, Wt + n0 * KDIM, KDIM, KDIM, lds, acc);
    __syncthreads();

    const int lane = threadIdx.x & 63, wave = threadIdx.x >> 6;
    const int wm = (wave >> 1) * 64, wn = (wave & 1) * 64;
    unsigned short* lw = lds + wave * 2560;
    const int region = n0 >> 10;
    const int nloc = n0 & 1023;
    if (region == 0)
        store_rows_bf16(acc, Qb + (m0 + wm) * KDIM + nloc + wn, KDIM, lw, lane);
    else if (region == 2)
        store_rows_bf16(acc, Kb + (m0 + wm) * KDIM + nloc + wn, KDIM, lw, lane);
    else
        store_cols_bf16(acc, Vt + (nloc + wn) * SEQ + m0 + wm, lw, lane);
}

// ---------------------------------------------------------------------------
// Kernel 2: fused score+exp. P = exp((Q@K^T)/32) causal (no max-sub: |s|<=16
// by Cauchy-Schwarz). Row sums atomicAdd into lrow; P bf16 to Sb.
// Grid (bm=32, bn=32), early-exit bn>bm.
// ---------------------------------------------------------------------------
__global__ __launch_bounds__(256) void score_exp_gemm(
    const unsigned short* __restrict__ Qb, const unsigned short* __restrict__ Kb,
    unsigned short* __restrict__ Sb, float* __restrict__ lrow)
{
    __shared__ __align__(16) unsigned short lds[24576];
    const int bm = blockIdx.x, bn = blockIdx.y;
    if (bn > bm) return;
    const int m0 = bm * 128, n0 = bn * 128;

    f32x4 acc[4][4];
    zero_acc(acc);
    mfma_pipe(Qb + m0 * KDIM, KDIM, Kb + n0 * KDIM, KDIM, KDIM, lds, acc);

    const int lane = threadIdx.x & 63, wave = threadIdx.x >> 6;
    const int lr = lane & 15, quad = lane >> 4;
    const int wm = (wave >> 1) * 64, wn = (wave & 1) * 64;
    #pragma unroll
    for (int i = 0; i < 4; ++i)
        #pragma unroll
        for (int j = 0; j < 4; ++j)
            #pragma unroll
            for (int r = 0; r < 4; ++r) {
                float v = __expf(acc[i][j][r] * 0.03125f);
                if (bm == bn) {
                    int row = wm + 16 * i + quad * 4 + r;
                    int col = wn + 16 * j + lr;
                    if (col > row) v = 0.f;
                }
                acc[i][j][r] = v;
            }
    #pragma unroll
    for (int i = 0; i < 4; ++i)
        #pragma unroll
        for (int r = 0; r < 4; ++r) {
            float s = acc[i][0][r] + acc[i][1][r] + acc[i][2][r] + acc[i][3][r];
            s += __shfl_xor(s, 1, 16);
            s += __shfl_xor(s, 2, 16);
            s += __shfl_xor(s, 4, 16);
            s += __shfl_xor(s, 8, 16);
            if (lr == 0)
                atomicAdd(&lrow[m0 + wm + 16 * i + quad * 4 + r], s);
        }
    __syncthreads();
    store_rows_bf16(acc, Sb + (m0 + wm) * SEQ + n0 + wn, SEQ, lds + wave * 2560, lane);
}

// ---------------------------------------------------------------------------
// Kernel 3: out = (P @ V) / l, split-K in 1024-wide chunks (atomic depth <=4).
// Grid dim3(x=n(8), y=pair(80)): lin = n + 8*pair -> same (m,n) tile's chunks
// land on one XCD (atomic locality; this orientation was R4's, the best pv).
// ---------------------------------------------------------------------------
__global__ __launch_bounds__(256) void pv_gemm(
    const unsigned short* __restrict__ Sb, const unsigned short* __restrict__ Vt,
    const float* __restrict__ lrow, float* __restrict__ out)
{
    __shared__ __align__(16) unsigned short lds[16384];   // 32 KiB
    const int n0 = blockIdx.x * 128;
    const int y = blockIdx.y;               // 0..79
    int m, c;
    if (y < 8)       { m = y;                 c = 0; }
    else if (y < 24) { m = 8 + (y - 8) / 2;   c = (y - 8) % 2; }
    else if (y < 48) { m = 16 + (y - 24) / 3; c = (y - 24) % 3; }
    else             { m = 24 + (y - 48) / 4; c = (y - 48) % 4; }
    const int m0 = m * 128;
    const int kstart = c * 1024;
    const int kend = min((m + 1) * 128, kstart + 1024);
    const int nchunks = (m >> 3) + 1;

    f32x4 acc[4][4];
    zero_acc(acc);
    mfma_db(Sb + m0 * SEQ + kstart, SEQ, Vt + n0 * SEQ + kstart, SEQ,
            kend - kstart, lds, acc);

    const int lane = threadIdx.x & 63, wave = threadIdx.x >> 6;
    const int lr = lane & 15, quad = lane >> 4;
    const int wm = (wave >> 1) * 64, wn = (wave & 1) * 64;
    #pragma unroll
    for (int i = 0; i < 4; ++i) {
        const int rbase = m0 + wm + 16 * i + quad * 4;
        const float4 l4 = *(const float4*)(lrow + rbase);
        float inv[4] = {1.0f / l4.x, 1.0f / l4.y, 1.0f / l4.z, 1.0f / l4.w};
        #pragma unroll
        for (int j = 0; j < 4; ++j) {
            const int col = n0 + wn + 16 * j + lr;
            if (nchunks == 1) {
                #pragma unroll
                for (int r = 0; r < 4; ++r)
                    out[(rbase + r) * KDIM + col] = acc[i][j][r] * inv[r];
            } else {
                #pragma unroll
                for (int r = 0; r < 4; ++r)
                    atomicAdd(&out[(rbase + r) * KDIM + col], acc[i][j][r] * inv[r]);
            }
        }
    }
}

// ---------------------------------------------------------------------------
extern "C" void kernel_launch(void* const* d_in, const int* in_sizes, int n_in,
                              void* d_out, int out_size, void* d_ws, size_t ws_size,
                              hipStream_t stream) {
    const float* x = (const float*)d_in[0];   // [4096][1024]
    const float* W = (const float*)d_in[1];   // [1024][3072]
    float* out = (float*)d_out;               // [4096][1024]
    char* ws = (char*)d_ws;

    unsigned short* Xb = (unsigned short*)(ws);                     //  8 MiB
    unsigned short* Wt = (unsigned short*)(ws + 8388608);           //  6 MiB
    unsigned short* Qb = (unsigned short*)(ws + 14680064);          //  8 MiB
    unsigned short* Kb = (unsigned short*)(ws + 23068672);          //  8 MiB
    unsigned short* Vt = (unsigned short*)(ws + 31457280);          //  8 MiB
    unsigned short* Sb = (unsigned short*)(ws + 39845888);          // 32 MiB
    float*        lrow = (float*)(ws + 73400320);                   // 16 KiB

    prep          <<<11265, 256, 0, stream>>>(x, Xb, W, Wt, (float4*)out, (float4*)lrow);
    qvk_gemm      <<<dim3(SEQ / 128, NQKV / 128), 256, 0, stream>>>(Xb, Wt, Qb, Kb, Vt);
    score_exp_gemm<<<dim3(SEQ / 128, SEQ / 128), 256, 0, stream>>>(Qb, Kb, Sb, lrow);
    pv_gemm       <<<dim3(KDIM / 128, 80), 256, 0, stream>>>(Sb, Vt, lrow, out);
}